// Round 2
// baseline (127.940 us; speedup 1.0000x reference)
//
#include <hip/hip_runtime.h>
#include <math.h>

#define NB 512
#define NS 64
#define ND 2048
#define NP 1024  // ND/2

// ---------------- threefry2x32 (exact jax semantics, key=(0,42)) -------------
__device__ __forceinline__ unsigned rotl32(unsigned x, int d) {
    return (x << d) | (x >> (32 - d));
}

__device__ __forceinline__ void threefry2x32(unsigned k0, unsigned k1,
                                             unsigned& x0, unsigned& x1) {
    const unsigned ks0 = k0, ks1 = k1, ks2 = k0 ^ k1 ^ 0x1BD11BDAu;
    const int r0[4] = {13, 15, 26, 6};
    const int r1[4] = {17, 29, 16, 24};
    x0 += ks0; x1 += ks1;
#pragma unroll
    for (int i = 0; i < 4; ++i) { x0 += x1; x1 = rotl32(x1, r0[i]); x1 ^= x0; }
    x0 += ks1; x1 += ks2 + 1u;
#pragma unroll
    for (int i = 0; i < 4; ++i) { x0 += x1; x1 = rotl32(x1, r1[i]); x1 ^= x0; }
    x0 += ks2; x1 += ks0 + 2u;
#pragma unroll
    for (int i = 0; i < 4; ++i) { x0 += x1; x1 = rotl32(x1, r0[i]); x1 ^= x0; }
    x0 += ks0; x1 += ks1 + 3u;
#pragma unroll
    for (int i = 0; i < 4; ++i) { x0 += x1; x1 = rotl32(x1, r1[i]); x1 ^= x0; }
    x0 += ks1; x1 += ks2 + 4u;
#pragma unroll
    for (int i = 0; i < 4; ++i) { x0 += x1; x1 = rotl32(x1, r0[i]); x1 ^= x0; }
    x0 += ks2; x1 += ks0 + 5u;
}

// ---------------- K1: row norms of amplitudes -> 1/norm ----------------------
__global__ void k_norms(const float* __restrict__ amp, float* __restrict__ inv_norm) {
    int t = blockIdx.x;
    const float* row = amp + t * ND;
    float s = 0.f;
    for (int d = threadIdx.x; d < ND; d += 256) { float v = row[d]; s += v * v; }
    __shared__ float red[256];
    red[threadIdx.x] = s;
    __syncthreads();
    for (int off = 128; off; off >>= 1) {
        if (threadIdx.x < off) red[threadIdx.x] += red[threadIdx.x + off];
        __syncthreads();
    }
    if (threadIdx.x == 0) inv_norm[t] = 1.0f / sqrtf(red[0]);
}

// ---------------- K2: softmax rows of entanglement matrix --------------------
__global__ void k_softmax(const float* __restrict__ E, float* __restrict__ Wm) {
    int srow = blockIdx.x;
    int t = threadIdx.x;  // 64 threads = one wave
    float e = E[srow * NS + t];
    float m = e;
    for (int off = 32; off; off >>= 1) m = fmaxf(m, __shfl_down(m, off));
    m = __shfl(m, 0);
    float ex = expf(e - m);
    float sum = ex;
    for (int off = 32; off; off >>= 1) sum += __shfl_down(sum, off);
    sum = __shfl(sum, 0);
    Wm[srow * NS + t] = ex / sum;
}

// ---------------- K3: ra[t,d] = amp/norm * (cos+sin)(phase) ------------------
__global__ void k_ra(const float* __restrict__ amp, const float* __restrict__ ph,
                     const float* __restrict__ inv_norm, float* __restrict__ ra) {
    int idx = blockIdx.x * 256 + threadIdx.x;  // < NS*ND
    int t = idx >> 11;
    float p = ph[idx];
    ra[idx] = amp[idx] * inv_norm[t] * (cosf(p) + sinf(p));
}

// ---------------- K4: M0/M1[s,d] = sum_t W[s,t]*ra[t,d]*G[t,i,d&1] -----------
__global__ void k_M(const float* __restrict__ Wm, const float* __restrict__ G,
                    const float* __restrict__ ra,
                    float* __restrict__ M0, float* __restrict__ M1) {
    __shared__ float Wrow[NS];
    __shared__ float Gl[NS * 4];
    int srow = blockIdx.x >> 3;
    int d = ((blockIdx.x & 7) << 8) + threadIdx.x;
    if (threadIdx.x < NS) Wrow[threadIdx.x] = Wm[srow * NS + threadIdx.x];
    Gl[threadIdx.x] = G[threadIdx.x];  // 256 = NS*4
    __syncthreads();
    int j = d & 1;
    float m0 = 0.f, m1 = 0.f;
#pragma unroll 8
    for (int t = 0; t < NS; ++t) {
        float wr = Wrow[t] * ra[t * ND + d];
        m0 += wr * Gl[t * 4 + j];
        m1 += wr * Gl[t * 4 + 2 + j];
    }
    M0[srow * ND + d] = m0;
    M1[srow * ND + d] = m1;
}

// ---------------- K5: per-pair quadratic coeffs, transposed [3P][S] ----------
__global__ void k_Q(const float* __restrict__ M0, const float* __restrict__ M1,
                    float* __restrict__ Qt) {
    int idx = blockIdx.x * 256 + threadIdx.x;  // < NS*NP
    int s = idx & (NS - 1);
    int p = idx >> 6;
    float a0 = M0[s * ND + 2 * p], a1 = M0[s * ND + 2 * p + 1];
    float b0 = M1[s * ND + 2 * p], b1 = M1[s * ND + 2 * p + 1];
    Qt[(3 * p + 0) * NS + s] = a0 * a0 + a1 * a1;
    Qt[(3 * p + 1) * NS + s] = a0 * b0 + a1 * b1;
    Qt[(3 * p + 2) * NS + s] = b0 * b0 + b1 * b1;
}

// ---------------- K6: split-K logits GEMM: part[ks][b][s] --------------------
__global__ void k_logits(const float* __restrict__ x, const float* __restrict__ Qt,
                         float* __restrict__ part) {
    int bt = blockIdx.x;   // 0..31 (16 b-rows each)
    int ks = blockIdx.y;   // 0..3  (256 pairs each)
    int w = threadIdx.x >> 6, lane = threadIdx.x & 63;
    int b0 = bt * 16 + w * 4;
    const float2* xp = (const float2*)x;
    float acc0 = 0.f, acc1 = 0.f, acc2 = 0.f, acc3 = 0.f;
    int p0 = ks * 256;
    for (int p = p0; p < p0 + 256; ++p) {
        float q0 = Qt[(3 * p + 0) * NS + lane];
        float q1 = Qt[(3 * p + 1) * NS + lane];
        float q2 = Qt[(3 * p + 2) * NS + lane];
        float2 v0 = xp[(b0 + 0) * NP + p];
        float2 v1 = xp[(b0 + 1) * NP + p];
        float2 v2 = xp[(b0 + 2) * NP + p];
        float2 v3 = xp[(b0 + 3) * NP + p];
        acc0 += v0.x * v0.x * q0 + 2.f * v0.x * v0.y * q1 + v0.y * v0.y * q2;
        acc1 += v1.x * v1.x * q0 + 2.f * v1.x * v1.y * q1 + v1.y * v1.y * q2;
        acc2 += v2.x * v2.x * q0 + 2.f * v2.x * v2.y * q1 + v2.y * v2.y * q2;
        acc3 += v3.x * v3.x * q0 + 2.f * v3.x * v3.y * q1 + v3.y * v3.y * q2;
    }
    part[(ks * NB + b0 + 0) * NS + lane] = acc0;
    part[(ks * NB + b0 + 1) * NS + lane] = acc1;
    part[(ks * NB + b0 + 2) * NS + lane] = acc2;
    part[(ks * NB + b0 + 3) * NS + lane] = acc3;
}

// ---------------- K7: gumbel-max collapse (jax categorical, partitionable) ---
// jax_threefry_partitionable=True (default in modern jax): element n's bits are
// threefry2x32(key, (hi32(n), lo32(n))) with the two outputs XOR-folded for a
// 32-bit draw. n < 2^32 here, so x0 = 0, x1 = n.
__global__ void k_collapse(const float* __restrict__ part, int* __restrict__ outcome) {
    int b = blockIdx.x;
    int s = threadIdx.x;  // 64 threads = one wave
    float l = part[(0 * NB + b) * NS + s] + part[(1 * NB + b) * NS + s] +
              part[(2 * NB + b) * NS + s] + part[(3 * NB + b) * NS + s];
    unsigned n = (unsigned)(b * NS + s);
    unsigned x0 = 0u, x1 = n;
    threefry2x32(0u, 42u, x0, x1);
    unsigned bits = x0 ^ x1;
    // jax uniform: bitcast(bits>>9 | 0x3f800000) - 1 == (bits>>9)*2^-23 exactly;
    // *(1-tiny)+tiny is identity in fp32 except u==0; then max(tiny, .)
    float u = (float)(bits >> 9) * (1.0f / 8388608.0f);
    u = fmaxf(u, 1.17549435e-38f);
    float g = -logf(-logf(u));
    float v = l + g;
    float best = v;
    int bi = s;
    for (int off = 32; off; off >>= 1) {
        float ov = __shfl_down(best, off);
        int oi = __shfl_down(bi, off);
        if (ov > best || (ov == best && oi < bi)) { best = ov; bi = oi; }
    }
    if (s == 0) outcome[b] = bi;
}

// ---------------- K8: gather + final linear map ------------------------------
__global__ void k_out(const float* __restrict__ x, const float* __restrict__ M0,
                      const float* __restrict__ M1, const int* __restrict__ outcome,
                      float* __restrict__ out) {
    int idx = blockIdx.x * 256 + threadIdx.x;  // < NB*NP
    int b = idx >> 10;
    int p = idx & 1023;
    int o = outcome[b];
    const float2* xp = (const float2*)x;
    float2 xv = xp[idx];
    const float2* m0p = (const float2*)(M0 + o * ND);
    const float2* m1p = (const float2*)(M1 + o * ND);
    float2 m0 = m0p[p], m1 = m1p[p];
    float2 r;
    r.x = xv.x * m0.x + xv.y * m1.x;
    r.y = xv.x * m0.y + xv.y * m1.y;
    ((float2*)out)[idx] = r;
}

extern "C" void kernel_launch(void* const* d_in, const int* in_sizes, int n_in,
                              void* d_out, int out_size, void* d_ws, size_t ws_size,
                              hipStream_t stream) {
    const float* x   = (const float*)d_in[0];  // [512,2048]
    const float* amp = (const float*)d_in[1];  // [64,2048]
    const float* ph  = (const float*)d_in[2];  // [64,2048]
    const float* G   = (const float*)d_in[3];  // [64,2,2]
    const float* E   = (const float*)d_in[4];  // [64,64]
    float* out = (float*)d_out;
    float* ws = (float*)d_ws;

    // ws layout (float offsets); total ~2.9 MB
    float* Wm       = ws;               // 4096
    float* inv_norm = ws + 4096;        // 64
    float* ra       = ws + 4160;        // 131072
    float* M0       = ws + 135232;      // 131072
    float* M1       = ws + 266304;      // 131072
    float* Qt       = ws + 397376;      // 196608
    float* part     = ws + 593984;      // 4*512*64 = 131072
    int*   outcome  = (int*)(ws + 725056);  // 512 ints

    k_norms  <<<64,   256, 0, stream>>>(amp, inv_norm);
    k_softmax<<<64,    64, 0, stream>>>(E, Wm);
    k_ra     <<<512,  256, 0, stream>>>(amp, ph, inv_norm, ra);
    k_M      <<<512,  256, 0, stream>>>(Wm, G, ra, M0, M1);
    k_Q      <<<256,  256, 0, stream>>>(M0, M1, Qt);
    k_logits <<<dim3(32, 4), 256, 0, stream>>>(x, Qt, part);
    k_collapse<<<512,  64, 0, stream>>>(part, outcome);
    k_out    <<<2048, 256, 0, stream>>>(x, M0, M1, outcome, out);
}

// Round 3
// 117.465 us; speedup vs baseline: 1.0892x; 1.0892x over previous
//
#include <hip/hip_runtime.h>
#include <math.h>

#define NB 512
#define NS 64
#define ND 2048
#define NP 1024  // ND/2

// ---------------- threefry2x32 (exact jax semantics, key=(0,42)) -------------
__device__ __forceinline__ unsigned rotl32(unsigned x, int d) {
    return (x << d) | (x >> (32 - d));
}

__device__ __forceinline__ void threefry2x32(unsigned k0, unsigned k1,
                                             unsigned& x0, unsigned& x1) {
    const unsigned ks0 = k0, ks1 = k1, ks2 = k0 ^ k1 ^ 0x1BD11BDAu;
    const int r0[4] = {13, 15, 26, 6};
    const int r1[4] = {17, 29, 16, 24};
    x0 += ks0; x1 += ks1;
#pragma unroll
    for (int i = 0; i < 4; ++i) { x0 += x1; x1 = rotl32(x1, r0[i]); x1 ^= x0; }
    x0 += ks1; x1 += ks2 + 1u;
#pragma unroll
    for (int i = 0; i < 4; ++i) { x0 += x1; x1 = rotl32(x1, r1[i]); x1 ^= x0; }
    x0 += ks2; x1 += ks0 + 2u;
#pragma unroll
    for (int i = 0; i < 4; ++i) { x0 += x1; x1 = rotl32(x1, r0[i]); x1 ^= x0; }
    x0 += ks0; x1 += ks1 + 3u;
#pragma unroll
    for (int i = 0; i < 4; ++i) { x0 += x1; x1 = rotl32(x1, r1[i]); x1 ^= x0; }
    x0 += ks1; x1 += ks2 + 4u;
#pragma unroll
    for (int i = 0; i < 4; ++i) { x0 += x1; x1 = rotl32(x1, r0[i]); x1 ^= x0; }
    x0 += ks2; x1 += ks0 + 5u;
}

// ---------------- K1: fused norms (blocks 0-63) + softmax (blocks 64-127) ----
__global__ void k_prep(const float* __restrict__ amp, const float* __restrict__ E,
                       float* __restrict__ inv_norm, float* __restrict__ Wm) {
    int blk = blockIdx.x;
    if (blk < 64) {
        const float* row = amp + blk * ND;
        float s = 0.f;
        for (int d = threadIdx.x; d < ND; d += 256) { float v = row[d]; s += v * v; }
        __shared__ float red[256];
        red[threadIdx.x] = s;
        __syncthreads();
        for (int off = 128; off; off >>= 1) {
            if (threadIdx.x < off) red[threadIdx.x] += red[threadIdx.x + off];
            __syncthreads();
        }
        if (threadIdx.x == 0) inv_norm[blk] = 1.0f / sqrtf(red[0]);
    } else {
        int srow = blk - 64;
        int t = threadIdx.x;
        if (t < 64) {  // one wave does the 64-wide softmax row
            float e = E[srow * NS + t];
            float m = e;
            for (int off = 32; off; off >>= 1) m = fmaxf(m, __shfl_down(m, off));
            m = __shfl(m, 0);
            float ex = expf(e - m);
            float sum = ex;
            for (int off = 32; off; off >>= 1) sum += __shfl_down(sum, off);
            sum = __shfl(sum, 0);
            Wm[srow * NS + t] = ex / sum;
        }
    }
}

// ---------------- K2: fused ra + M0/M1 + Qt ----------------------------------
// ra recomputed on the fly (amp/ph are L2-resident; saves a kernel + buffer).
// Qt[(3p+i)*NS+s] written by even lanes after __shfl_xor pair-reduction.
__global__ void k_MQ(const float* __restrict__ amp, const float* __restrict__ ph,
                     const float* __restrict__ inv_norm, const float* __restrict__ Wm,
                     const float* __restrict__ G,
                     float* __restrict__ M0, float* __restrict__ M1,
                     float* __restrict__ Qt) {
    __shared__ float Wrow[NS];
    __shared__ float invn[NS];
    __shared__ float Gl[NS * 4];
    int srow = blockIdx.x >> 3;
    int d = ((blockIdx.x & 7) << 8) + threadIdx.x;
    if (threadIdx.x < NS) {
        Wrow[threadIdx.x] = Wm[srow * NS + threadIdx.x];
        invn[threadIdx.x] = inv_norm[threadIdx.x];
    }
    Gl[threadIdx.x] = G[threadIdx.x];  // 256 = NS*4
    __syncthreads();
    int j = d & 1;
    float m0 = 0.f, m1 = 0.f;
#pragma unroll 4
    for (int t = 0; t < NS; ++t) {
        float p = ph[t * ND + d];
        float ra = amp[t * ND + d] * invn[t] * (__cosf(p) + __sinf(p));
        float wr = Wrow[t] * ra;
        m0 += wr * Gl[t * 4 + j];
        m1 += wr * Gl[t * 4 + 2 + j];
    }
    M0[srow * ND + d] = m0;
    M1[srow * ND + d] = m1;
    // quadratic coeffs per pair: q0=a0^2+a1^2, q1=a0b0+a1b1, q2=b0^2+b1^2
    float c0 = m0 * m0, c1 = m0 * m1, c2 = m1 * m1;
    c0 += __shfl_xor(c0, 1);
    c1 += __shfl_xor(c1, 1);
    c2 += __shfl_xor(c2, 1);
    if (j == 0) {
        int p = d >> 1;
        Qt[(3 * p + 0) * NS + srow] = c0;
        Qt[(3 * p + 1) * NS + srow] = c1;
        Qt[(3 * p + 2) * NS + srow] = c2;
    }
}

// ---------------- K3: split-K logits GEMM: part[ks][b][s] --------------------
__global__ void k_logits(const float* __restrict__ x, const float* __restrict__ Qt,
                         float* __restrict__ part, int chunk) {
    int bt = blockIdx.x;   // 0..31 (16 b-rows each)
    int ks = blockIdx.y;   // 0..nsplit-1
    int w = threadIdx.x >> 6, lane = threadIdx.x & 63;
    int b0 = bt * 16 + w * 4;
    const float2* xp = (const float2*)x;
    float acc0 = 0.f, acc1 = 0.f, acc2 = 0.f, acc3 = 0.f;
    int p0 = ks * chunk;
#pragma unroll 4
    for (int p = p0; p < p0 + chunk; ++p) {
        float q0 = Qt[(3 * p + 0) * NS + lane];
        float q1 = Qt[(3 * p + 1) * NS + lane];
        float q2 = Qt[(3 * p + 2) * NS + lane];
        float2 v0 = xp[(b0 + 0) * NP + p];
        float2 v1 = xp[(b0 + 1) * NP + p];
        float2 v2 = xp[(b0 + 2) * NP + p];
        float2 v3 = xp[(b0 + 3) * NP + p];
        acc0 += v0.x * v0.x * q0 + 2.f * v0.x * v0.y * q1 + v0.y * v0.y * q2;
        acc1 += v1.x * v1.x * q0 + 2.f * v1.x * v1.y * q1 + v1.y * v1.y * q2;
        acc2 += v2.x * v2.x * q0 + 2.f * v2.x * v2.y * q1 + v2.y * v2.y * q2;
        acc3 += v3.x * v3.x * q0 + 2.f * v3.x * v3.y * q1 + v3.y * v3.y * q2;
    }
    part[(ks * NB + b0 + 0) * NS + lane] = acc0;
    part[(ks * NB + b0 + 1) * NS + lane] = acc1;
    part[(ks * NB + b0 + 2) * NS + lane] = acc2;
    part[(ks * NB + b0 + 3) * NS + lane] = acc3;
}

// ---------------- K4: gumbel-max collapse (jax categorical, partitionable) ---
__global__ void k_collapse(const float* __restrict__ part, int* __restrict__ outcome,
                           int nsplit) {
    int b = blockIdx.x;
    int s = threadIdx.x;  // 64 threads = one wave
    float l = 0.f;
    for (int k = 0; k < nsplit; ++k) l += part[(k * NB + b) * NS + s];
    unsigned n = (unsigned)(b * NS + s);
    unsigned x0 = 0u, x1 = n;  // partitionable: counter = (hi32(n), lo32(n))
    threefry2x32(0u, 42u, x0, x1);
    unsigned bits = x0 ^ x1;
    float u = (float)(bits >> 9) * (1.0f / 8388608.0f);
    u = fmaxf(u, 1.17549435e-38f);
    float g = -logf(-logf(u));
    float v = l + g;
    float best = v;
    int bi = s;
    for (int off = 32; off; off >>= 1) {
        float ov = __shfl_down(best, off);
        int oi = __shfl_down(bi, off);
        if (ov > best || (ov == best && oi < bi)) { best = ov; bi = oi; }
    }
    if (s == 0) outcome[b] = bi;
}

// ---------------- K5: gather + final linear map ------------------------------
__global__ void k_out(const float* __restrict__ x, const float* __restrict__ M0,
                      const float* __restrict__ M1, const int* __restrict__ outcome,
                      float* __restrict__ out) {
    int idx = blockIdx.x * 256 + threadIdx.x;  // < NB*NP
    int b = idx >> 10;
    int p = idx & 1023;
    int o = outcome[b];
    const float2* xp = (const float2*)x;
    float2 xv = xp[idx];
    const float2* m0p = (const float2*)(M0 + o * ND);
    const float2* m1p = (const float2*)(M1 + o * ND);
    float2 m0 = m0p[p], m1 = m1p[p];
    float2 r;
    r.x = xv.x * m0.x + xv.y * m1.x;
    r.y = xv.x * m0.y + xv.y * m1.y;
    ((float2*)out)[idx] = r;
}

extern "C" void kernel_launch(void* const* d_in, const int* in_sizes, int n_in,
                              void* d_out, int out_size, void* d_ws, size_t ws_size,
                              hipStream_t stream) {
    const float* x   = (const float*)d_in[0];  // [512,2048]
    const float* amp = (const float*)d_in[1];  // [64,2048]
    const float* ph  = (const float*)d_in[2];  // [64,2048]
    const float* G   = (const float*)d_in[3];  // [64,2,2]
    const float* E   = (const float*)d_in[4];  // [64,64]
    float* out = (float*)d_out;
    float* ws = (float*)d_ws;

    // ws layout (float offsets)
    float* Wm       = ws;                    // 4096
    float* inv_norm = ws + 4096;             // 64
    float* M0       = ws + 4160;             // 131072
    float* M1       = ws + 135232;           // 131072
    float* Qt       = ws + 266304;           // 3*1024*64 = 196608
    int*   outcome  = (int*)(ws + 462912);   // 512
    float* part     = ws + 463424;           // nsplit*512*64

    // pick largest split-K that fits the workspace (constant across calls)
    int nsplit = 16;
    while (nsplit > 2 && (size_t)(463424 + nsplit * NB * NS) * 4 > ws_size) nsplit >>= 1;
    int chunk = NP / nsplit;

    k_prep    <<<128, 256, 0, stream>>>(amp, E, inv_norm, Wm);
    k_MQ      <<<512, 256, 0, stream>>>(amp, ph, inv_norm, Wm, G, M0, M1, Qt);
    k_logits  <<<dim3(32, nsplit), 256, 0, stream>>>(x, Qt, part, chunk);
    k_collapse<<<512, 64, 0, stream>>>(part, outcome, nsplit);
    k_out     <<<2048, 256, 0, stream>>>(x, M0, M1, outcome, out);
}